// Round 1
// baseline (3385.828 us; speedup 1.0000x reference)
//
#include <hip/hip_runtime.h>

#define BB  32
#define TXX 2048
#define DHH 512
#define UU  1024

#define ROWS 64
#define JTW  128
#define DK   32

// ---------------------------------------------------------------------------
// K1: dec[b][j] = sum_k h[b][k] * Wh_w[k][j] + Wh_b[j]
// ---------------------------------------------------------------------------
__global__ __launch_bounds__(256) void dec_kernel(
    const float* __restrict__ h, const float* __restrict__ Whw,
    const float* __restrict__ Whb, float* __restrict__ dec) {
  int b = blockIdx.x;
  __shared__ float hs[DHH];
  for (int k = threadIdx.x; k < DHH; k += 256) hs[k] = h[b * DHH + k];
  __syncthreads();
  for (int j = threadIdx.x; j < UU; j += 256) {
    float acc = Whb[j];
    for (int k = 0; k < DHH; ++k) acc = fmaf(hs[k], Whw[(size_t)k * UU + j], acc);
    dec[b * UU + j] = acc;
  }
}

// ---------------------------------------------------------------------------
// K2: fused  e[b,t] = sum_j v[j] * tanh( (a[b,t,:] @ Wa)[j] + dec[b,j] + cov[b,t]*Wc[j] )
// Block: 64 rows (t) x full j sweep in tiles of 128. 256 threads = 16 (tr) x 16 (tc).
// Thread register tile: 4 rows (tr + 16*rr) x 8 cols (tc + 16*cc).
// ---------------------------------------------------------------------------
__global__ __launch_bounds__(256) void e_kernel(
    const float* __restrict__ a, const float* __restrict__ Wa,
    const float* __restrict__ dec, const float* __restrict__ cov,
    const float* __restrict__ Wc, const float* __restrict__ v,
    const int* __restrict__ use_cov_p, float* __restrict__ e_out) {
  __shared__ float aS[ROWS][36];   // pad 36: rows 16B-aligned, reads 2-way max
  __shared__ float wT[JTW][36];    // transposed Wa tile: wT[j][d]
  __shared__ float redS[16][16][4];

  const int tid = threadIdx.x;
  const int blk = blockIdx.x;
  const int b  = blk >> 5;
  const int t0 = (blk & 31) * ROWS;
  const float* __restrict__ abase = a + ((size_t)(b * TXX + t0)) * UU;
  const float* __restrict__ decb  = dec + b * UU;
  const int use_cov = *use_cov_p;

  const int tc = tid & 15;
  const int tr = tid >> 4;

  float covr[4];
#pragma unroll
  for (int rr = 0; rr < 4; ++rr)
    covr[rr] = use_cov ? cov[b * TXX + t0 + tr + 16 * rr] : 0.0f;

  float pe[4] = {0.f, 0.f, 0.f, 0.f};

  for (int jt = 0; jt < UU / JTW; ++jt) {
    const int j0 = jt * JTW;
    float acc[4][8];
#pragma unroll
    for (int rr = 0; rr < 4; ++rr)
#pragma unroll
      for (int cc = 0; cc < 8; ++cc) acc[rr][cc] = 0.f;

    for (int dk = 0; dk < UU / DK; ++dk) {
      const int d0 = dk * DK;
      // stage aS: 64 rows x 32 d  (512 float4, 2 per thread)
#pragma unroll
      for (int l = 0; l < 2; ++l) {
        int idx = tid + 256 * l;
        int row = idx >> 3, c4 = idx & 7;
        float4 va = *(const float4*)(abase + (size_t)row * UU + d0 + c4 * 4);
        float* dst = &aS[row][c4 * 4];
        dst[0] = va.x; dst[1] = va.y; dst[2] = va.z; dst[3] = va.w;
      }
      // stage wT (transposed): 32 d x 128 j  (1024 float4, 4 per thread)
#pragma unroll
      for (int l = 0; l < 4; ++l) {
        int idx = tid + 256 * l;
        int j4 = idx & 31, d = idx >> 5;
        float4 vw = *(const float4*)(Wa + (size_t)(d0 + d) * UU + j0 + j4 * 4);
        wT[j4 * 4 + 0][d] = vw.x;
        wT[j4 * 4 + 1][d] = vw.y;
        wT[j4 * 4 + 2][d] = vw.z;
        wT[j4 * 4 + 3][d] = vw.w;
      }
      __syncthreads();
#pragma unroll
      for (int db = 0; db < DK / 4; ++db) {
        float4 av[4], wv[8];
#pragma unroll
        for (int rr = 0; rr < 4; ++rr) av[rr] = *(const float4*)&aS[tr + 16 * rr][db * 4];
#pragma unroll
        for (int cc = 0; cc < 8; ++cc) wv[cc] = *(const float4*)&wT[tc + 16 * cc][db * 4];
#pragma unroll
        for (int rr = 0; rr < 4; ++rr)
#pragma unroll
          for (int cc = 0; cc < 8; ++cc) {
            acc[rr][cc] = fmaf(av[rr].x, wv[cc].x, acc[rr][cc]);
            acc[rr][cc] = fmaf(av[rr].y, wv[cc].y, acc[rr][cc]);
            acc[rr][cc] = fmaf(av[rr].z, wv[cc].z, acc[rr][cc]);
            acc[rr][cc] = fmaf(av[rr].w, wv[cc].w, acc[rr][cc]);
          }
      }
      __syncthreads();
    }
    // epilogue for this j-tile: pe[rr] += sum_cc v[j] * tanh(acc + dec[j] + cov*Wc[j])
#pragma unroll
    for (int rr = 0; rr < 4; ++rr) {
      float s = 0.f;
#pragma unroll
      for (int cc = 0; cc < 8; ++cc) {
        int j = j0 + tc + 16 * cc;
        float f = acc[rr][cc] + decb[j] + covr[rr] * Wc[j];
        s = fmaf(v[j], tanhf(f), s);
      }
      pe[rr] += s;
    }
  }

#pragma unroll
  for (int rr = 0; rr < 4; ++rr) redS[tr][tc][rr] = pe[rr];
  __syncthreads();
  if (tid < 64) {
    int trr = tid & 15, rr = tid >> 4;
    float s = 0.f;
#pragma unroll
    for (int q = 0; q < 16; ++q) s += redS[trr][q][rr];
    e_out[b * TXX + t0 + trr + 16 * rr] = s;
  }
}

// ---------------------------------------------------------------------------
// K3: masked softmax over TX.
// alpha[b,t] = m(t)*exp(e-M) / sum_t m(t)*exp(e-M)   (m==1 when !use_masking)
// Handles X_mask stored as either bool (1B) or int32 (4B) via deterministic
// layout sniff: int32-encoded 0/1 masks have all bytes at (i%4 != 0) == 0.
// ---------------------------------------------------------------------------
__global__ __launch_bounds__(256) void softmax_kernel(
    const float* __restrict__ e, const void* __restrict__ mask,
    const int* __restrict__ use_mask_p, float* __restrict__ alpha) {
  int b = blockIdx.x;
  int tid = threadIdx.x;
  int lane = tid & 63, wv = tid >> 6;
  const float* eb = e + b * TXX;
  const unsigned char* m8 = (const unsigned char*)mask;
  const int* m32 = (const int*)mask;
  int um = *use_mask_p;

  __shared__ int isBoolS;
  if (tid == 0) {
    int anyNZ = 0;
    for (int i = 0; i < 4096; ++i)
      if ((i & 3) && m8[i]) { anyNZ = 1; break; }
    isBoolS = anyNZ;
  }
  __syncthreads();
  const int isBool = isBoolS;

  // max
  float m = -1e30f;
  for (int t = tid; t < TXX; t += 256) m = fmaxf(m, eb[t]);
#pragma unroll
  for (int o = 32; o > 0; o >>= 1) m = fmaxf(m, __shfl_xor(m, o, 64));
  __shared__ float redm[4];
  if (lane == 0) redm[wv] = m;
  __syncthreads();
  m = fmaxf(fmaxf(redm[0], redm[1]), fmaxf(redm[2], redm[3]));

  // masked sum
  float s = 0.f;
  for (int t = tid; t < TXX; t += 256) {
    float w = __expf(eb[t] - m);
    if (um) {
      int mv = isBool ? (int)m8[b * TXX + t] : m32[b * TXX + t];
      if (mv == 0) w = 0.f;
    }
    s += w;
  }
#pragma unroll
  for (int o = 32; o > 0; o >>= 1) s += __shfl_xor(s, o, 64);
  __shared__ float reds[4];
  if (lane == 0) reds[wv] = s;
  __syncthreads();
  s = reds[0] + reds[1] + reds[2] + reds[3];
  float inv = 1.0f / s;

  for (int t = tid; t < TXX; t += 256) {
    float w = __expf(eb[t] - m);
    if (um) {
      int mv = isBool ? (int)m8[b * TXX + t] : m32[b * TXX + t];
      if (mv == 0) w = 0.f;
    }
    alpha[b * TXX + t] = w * inv;
  }
}

// ---------------------------------------------------------------------------
// K4: context[b,d] = sum_t alpha[b,t] * a[b,t,d]
// grid = 32 b x 8 d-tiles of 128; 256 threads = 128 cols x 2 t-halves
// ---------------------------------------------------------------------------
__global__ __launch_bounds__(256) void context_kernel(
    const float* __restrict__ a, const float* __restrict__ alpha,
    float* __restrict__ ctx) {
  int b = blockIdx.x >> 3;
  int d0 = (blockIdx.x & 7) * 128;
  int c = threadIdx.x & 127, hf = threadIdx.x >> 7;
  const float* __restrict__ ab  = a + ((size_t)b * TXX) * UU + d0;
  const float* __restrict__ alb = alpha + b * TXX;
  float acc = 0.f;
  for (int t = hf; t < TXX; t += 2)
    acc = fmaf(alb[t], ab[(size_t)t * UU + c], acc);
  __shared__ float s2[2][128];
  s2[hf][c] = acc;
  __syncthreads();
  if (hf == 0) ctx[b * UU + d0 + c] = s2[0][c] + s2[1][c];
}

// ---------------------------------------------------------------------------
extern "C" void kernel_launch(void* const* d_in, const int* in_sizes, int n_in,
                              void* d_out, int out_size, void* d_ws, size_t ws_size,
                              hipStream_t stream) {
  const float* a    = (const float*)d_in[0];
  const float* h    = (const float*)d_in[1];
  const float* cov  = (const float*)d_in[2];
  const void*  msk  = d_in[3];
  const float* Wa   = (const float*)d_in[4];
  const float* Whw  = (const float*)d_in[5];
  const float* Whb  = (const float*)d_in[6];
  const float* Wc   = (const float*)d_in[7];
  const float* v    = (const float*)d_in[8];
  const int* use_cov  = (const int*)d_in[9];
  const int* use_mask = (const int*)d_in[10];

  float* ws  = (float*)d_ws;
  float* dec = ws;             // 32*1024 floats
  float* e   = ws + BB * UU;   // 32*2048 floats

  float* ctx   = (float*)d_out;            // 32*1024
  float* alpha = (float*)d_out + BB * UU;  // 32*2048

  dec_kernel<<<BB, 256, 0, stream>>>(h, Whw, Whb, dec);
  e_kernel<<<BB * (TXX / ROWS), 256, 0, stream>>>(a, Wa, dec, cov, Wc, v, use_cov, e);
  softmax_kernel<<<BB, 256, 0, stream>>>(e, msk, use_mask, alpha);
  context_kernel<<<BB * 8, 256, 0, stream>>>(a, alpha, ctx);
}

// Round 2
// 819.187 us; speedup vs baseline: 4.1332x; 4.1332x over previous
//
#include <hip/hip_runtime.h>
#include <hip/hip_bf16.h>

#define BB  32
#define TXX 2048
#define DHH 512
#define UU  1024
#define MM  (BB*TXX)   // 65536

typedef __attribute__((ext_vector_type(8))) short s8v;
typedef __attribute__((ext_vector_type(4))) float f4v;

__device__ __forceinline__ ushort f2bf(float f) {
  return __builtin_bit_cast(ushort, __float2bfloat16(f));
}

__device__ __forceinline__ float tanh_fast(float x) {
  float ax = fabsf(x);
  float e2 = __expf(-2.0f * ax);
  float t = (1.0f - e2) * __builtin_amdgcn_rcpf(1.0f + e2);
  return copysignf(t, x);
}

// ---------------------------------------------------------------------------
// K0: WaT[j][k] = bf16(Wa[k][j])   (1024x1024), LDS-tiled transpose
// ---------------------------------------------------------------------------
__global__ __launch_bounds__(256) void watrans_kernel(
    const float* __restrict__ Wa, ushort* __restrict__ WaT) {
  __shared__ float Ts[64][65];
  const int jb = blockIdx.x & 15, kb = blockIdx.x >> 4;
  const int c = threadIdx.x & 63, r0 = threadIdx.x >> 6;
#pragma unroll
  for (int i = 0; i < 16; ++i) {
    int kl = r0 + 4 * i;
    Ts[c][kl] = Wa[(size_t)(kb * 64 + kl) * UU + jb * 64 + c];
  }
  __syncthreads();
#pragma unroll
  for (int i = 0; i < 16; ++i) {
    int jl = r0 + 4 * i;
    WaT[(size_t)(jb * 64 + jl) * UU + kb * 64 + c] = f2bf(Ts[jl][c]);
  }
}

// ---------------------------------------------------------------------------
// K1: dec[b][j] = h[b] @ Wh_w + Wh_b
// ---------------------------------------------------------------------------
__global__ __launch_bounds__(256) void dec_kernel(
    const float* __restrict__ h, const float* __restrict__ Whw,
    const float* __restrict__ Whb, float* __restrict__ dec) {
  int b = blockIdx.x;
  __shared__ float hs[DHH];
  for (int k = threadIdx.x; k < DHH; k += 256) hs[k] = h[b * DHH + k];
  __syncthreads();
  for (int j = threadIdx.x; j < UU; j += 256) {
    float acc = Whb[j];
    for (int k = 0; k < DHH; ++k) acc = fmaf(hs[k], Whw[(size_t)k * UU + j], acc);
    dec[b * UU + j] = acc;
  }
}

// ---------------------------------------------------------------------------
// K2: MFMA GEMM (M=65536,N=1024,K=1024) + fused tanh/v epilogue.
// partial[nt][m] = sum_{j in nt-tile} v_j tanh(enc[m][j] + dec[j] + cov[m]*Wc[j])
// 128x128 tile, BK=32, 4 waves 2x2, frags 4x4 of 16x16x32 bf16.
// LDS layout (A and B): [frag(8)][kslice(4)][idx15(16)] x 16B -> conflict-free b128.
// ---------------------------------------------------------------------------
__global__ __launch_bounds__(256) void e_mfma_kernel(
    const float* __restrict__ a, const ushort* __restrict__ WaT,
    const float* __restrict__ dec, const float* __restrict__ cov,
    const float* __restrict__ Wc, const float* __restrict__ v,
    const int* __restrict__ use_cov_p, float* __restrict__ partial) {
  __shared__ __align__(16) ushort aS[4096];   // 8 KB
  __shared__ __align__(16) ushort bS[4096];   // 8 KB
  __shared__ float dec_s[128], v_s[128], wc_s[128], cov_s[128];
  __shared__ float peL[2][128];

  const int tid = threadIdx.x;
  const int lane = tid & 63;
  const int wid = tid >> 6;
  const int wm = wid >> 1, wn = wid & 1;
  const int nt = blockIdx.x & 7;
  const int mt = blockIdx.x >> 3;
  const int j0 = nt * 128;
  const int row0 = mt * 128;
  const int b = row0 >> 11;
  const int trow0 = row0 & (TXX - 1);

  if (tid < 128) {
    dec_s[tid] = dec[b * UU + j0 + tid];
    v_s[tid] = v[j0 + tid];
    wc_s[tid] = Wc[j0 + tid];
    cov_s[tid] = (*use_cov_p) ? cov[b * TXX + trow0 + tid] : 0.0f;
  }

  f4v zero = {0.f, 0.f, 0.f, 0.f};
  f4v acc[4][4];
#pragma unroll
  for (int mi = 0; mi < 4; ++mi)
#pragma unroll
    for (int ni = 0; ni < 4; ++ni) acc[mi][ni] = zero;

  const float* __restrict__ aRow = a + (size_t)row0 * UU;
  const int arow = tid >> 3;        // 0..31
  const int kq = (tid & 7) * 4;     // 0..28

  for (int ks = 0; ks < 32; ++ks) {
    const int k0 = ks * 32;
    // --- stage A: 128 rows x 32 k, f32 -> bf16 ---
#pragma unroll
    for (int l = 0; l < 4; ++l) {
      const int row = l * 32 + arow;
      float4 va = *(const float4*)(aRow + (size_t)row * UU + k0 + kq);
      ushort4 ub = make_ushort4(f2bf(va.x), f2bf(va.y), f2bf(va.z), f2bf(va.w));
      const int unit = ((row >> 4) << 6) | ((kq >> 3) << 4) | (row & 15);
      *(ushort4*)&aS[unit * 8 + (kq & 7)] = ub;
    }
    // --- stage B: 128 j x 32 k bf16 (already transposed) ---
#pragma unroll
    for (int l = 0; l < 2; ++l) {
      const int u = l * 256 + tid;
      const int fn = u >> 6, kh = (u >> 4) & 3, j15 = u & 15;
      *(uint4*)&bS[u * 8] =
          *(const uint4*)(WaT + (size_t)(j0 + fn * 16 + j15) * UU + k0 + kh * 8);
    }
    __syncthreads();
    s8v af[4], bff[4];
#pragma unroll
    for (int mi = 0; mi < 4; ++mi)
      af[mi] = *(const s8v*)&aS[(((((wm << 2) + mi) << 6) | ((lane >> 4) << 4) | (lane & 15)) << 3)];
#pragma unroll
    for (int ni = 0; ni < 4; ++ni)
      bff[ni] = *(const s8v*)&bS[(((((wn << 2) + ni) << 6) | ((lane >> 4) << 4) | (lane & 15)) << 3)];
#pragma unroll
    for (int mi = 0; mi < 4; ++mi)
#pragma unroll
      for (int ni = 0; ni < 4; ++ni)
        acc[mi][ni] = __builtin_amdgcn_mfma_f32_16x16x32_bf16(af[mi], bff[ni], acc[mi][ni], 0, 0, 0);
    __syncthreads();
  }

  // --- epilogue: f = acc + dec[j] + cov[m]*Wc[j]; pe[m] += v[j]*tanh(f) ---
  const int lj = lane & 15, lk = lane >> 4;
  float pe[4][4];
#pragma unroll
  for (int mi = 0; mi < 4; ++mi)
#pragma unroll
    for (int r = 0; r < 4; ++r) pe[mi][r] = 0.f;

#pragma unroll
  for (int mi = 0; mi < 4; ++mi) {
    float cv[4];
#pragma unroll
    for (int r = 0; r < 4; ++r) cv[r] = cov_s[(wm << 6) + (mi << 4) + (lk << 2) + r];
#pragma unroll
    for (int ni = 0; ni < 4; ++ni) {
      const int jl = (wn << 6) + (ni << 4) + lj;
      const float dj = dec_s[jl], wj = wc_s[jl], vj = v_s[jl];
#pragma unroll
      for (int r = 0; r < 4; ++r) {
        float f = acc[mi][ni][r] + dj + cv[r] * wj;
        pe[mi][r] += vj * tanh_fast(f);
      }
    }
  }
#pragma unroll
  for (int mi = 0; mi < 4; ++mi)
#pragma unroll
    for (int r = 0; r < 4; ++r) {
      float s = pe[mi][r];
      s += __shfl_xor(s, 1); s += __shfl_xor(s, 2);
      s += __shfl_xor(s, 4); s += __shfl_xor(s, 8);
      if (lj == 0) peL[wn][(wm << 6) + (mi << 4) + (lk << 2) + r] = s;
    }
  __syncthreads();
  if (tid < 128)
    partial[(size_t)nt * MM + row0 + tid] = peL[0][tid] + peL[1][tid];
}

// ---------------------------------------------------------------------------
// K3: e = sum of 8 partials; masked softmax over TX.
// ---------------------------------------------------------------------------
__global__ __launch_bounds__(256) void softmax_kernel(
    const float* __restrict__ partial, const void* __restrict__ mask,
    const int* __restrict__ use_mask_p, float* __restrict__ alpha) {
  int b = blockIdx.x;
  int tid = threadIdx.x;
  int lane = tid & 63, wv = tid >> 6;
  const unsigned char* m8 = (const unsigned char*)mask;
  const int* m32 = (const int*)mask;
  int um = *use_mask_p;

  __shared__ float es[TXX];
  for (int t = tid; t < TXX; t += 256) {
    float s = 0.f;
#pragma unroll
    for (int nt = 0; nt < 8; ++nt) s += partial[(size_t)nt * MM + b * TXX + t];
    es[t] = s;
  }

  __shared__ int isBoolS;
  if (tid == 0) {
    int anyNZ = 0;
    for (int i = 0; i < 4096; ++i)
      if ((i & 3) && m8[i]) { anyNZ = 1; break; }
    isBoolS = anyNZ;
  }
  __syncthreads();
  const int isBool = isBoolS;

  float m = -1e30f;
  for (int t = tid; t < TXX; t += 256) m = fmaxf(m, es[t]);
#pragma unroll
  for (int o = 32; o > 0; o >>= 1) m = fmaxf(m, __shfl_xor(m, o, 64));
  __shared__ float redm[4];
  if (lane == 0) redm[wv] = m;
  __syncthreads();
  m = fmaxf(fmaxf(redm[0], redm[1]), fmaxf(redm[2], redm[3]));

  float s = 0.f;
  for (int t = tid; t < TXX; t += 256) {
    float w = __expf(es[t] - m);
    if (um) {
      int mv = isBool ? (int)m8[b * TXX + t] : m32[b * TXX + t];
      if (mv == 0) w = 0.f;
    }
    s += w;
  }
#pragma unroll
  for (int o = 32; o > 0; o >>= 1) s += __shfl_xor(s, o, 64);
  __shared__ float reds[4];
  if (lane == 0) reds[wv] = s;
  __syncthreads();
  s = reds[0] + reds[1] + reds[2] + reds[3];
  float inv = 1.0f / s;

  for (int t = tid; t < TXX; t += 256) {
    float w = __expf(es[t] - m);
    if (um) {
      int mv = isBool ? (int)m8[b * TXX + t] : m32[b * TXX + t];
      if (mv == 0) w = 0.f;
    }
    alpha[b * TXX + t] = w * inv;
  }
}

// ---------------------------------------------------------------------------
// K4: context[b,d] = sum_t alpha[b,t] * a[b,t,d]
// ---------------------------------------------------------------------------
__global__ __launch_bounds__(256) void context_kernel(
    const float* __restrict__ a, const float* __restrict__ alpha,
    float* __restrict__ ctx) {
  int b = blockIdx.x >> 3;
  int d0 = (blockIdx.x & 7) * 128;
  int c = threadIdx.x & 127, hf = threadIdx.x >> 7;
  const float* __restrict__ ab = a + ((size_t)b * TXX) * UU + d0;
  const float* __restrict__ alb = alpha + b * TXX;
  float acc0 = 0.f, acc1 = 0.f;
  for (int t = hf * 2; t < TXX; t += 4) {
    acc0 = fmaf(alb[t], ab[(size_t)t * UU + c], acc0);
    acc1 = fmaf(alb[t + 1], ab[(size_t)(t + 1) * UU + c], acc1);
  }
  __shared__ float s2[2][128];
  s2[hf][c] = acc0 + acc1;
  __syncthreads();
  if (hf == 0) ctx[b * UU + d0 + c] = s2[0][c] + s2[1][c];
}

// ---------------------------------------------------------------------------
extern "C" void kernel_launch(void* const* d_in, const int* in_sizes, int n_in,
                              void* d_out, int out_size, void* d_ws, size_t ws_size,
                              hipStream_t stream) {
  const float* a   = (const float*)d_in[0];
  const float* h   = (const float*)d_in[1];
  const float* cov = (const float*)d_in[2];
  const void*  msk = d_in[3];
  const float* Wa  = (const float*)d_in[4];
  const float* Whw = (const float*)d_in[5];
  const float* Whb = (const float*)d_in[6];
  const float* Wc  = (const float*)d_in[7];
  const float* v   = (const float*)d_in[8];
  const int* use_cov  = (const int*)d_in[9];
  const int* use_mask = (const int*)d_in[10];

  float*  dec     = (float*)d_ws;                                  // 128 KB
  ushort* WaT     = (ushort*)((char*)d_ws + 131072);               // 2 MB
  float*  partial = (float*)((char*)d_ws + 131072 + 2097152);      // 2 MB

  float* ctx   = (float*)d_out;
  float* alpha = (float*)d_out + BB * UU;

  watrans_kernel<<<256, 256, 0, stream>>>(Wa, WaT);
  dec_kernel<<<BB, 256, 0, stream>>>(h, Whw, Whb, dec);
  e_mfma_kernel<<<(MM / 128) * 8, 256, 0, stream>>>(a, WaT, dec, cov, Wc, v, use_cov, partial);
  softmax_kernel<<<BB, 256, 0, stream>>>(partial, msk, use_mask, alpha);
  context_kernel<<<BB * 8, 256, 0, stream>>>(a, alpha, ctx);
}

// Round 3
// 534.711 us; speedup vs baseline: 6.3321x; 1.5320x over previous
//
#include <hip/hip_runtime.h>
#include <hip/hip_bf16.h>

#define BB  32
#define TXX 2048
#define DHH 512
#define UU  1024
#define MM  (BB*TXX)   // 65536

typedef __attribute__((ext_vector_type(8))) short s8v;
typedef __attribute__((ext_vector_type(4))) float f4v;

__device__ __forceinline__ ushort f2bf(float f) {
  return __builtin_bit_cast(ushort, __float2bfloat16(f));
}

__device__ __forceinline__ float tanh_fast(float x) {
  float ax = fabsf(x);
  float e2 = __expf(-2.0f * ax);
  float t = (1.0f - e2) * __builtin_amdgcn_rcpf(1.0f + e2);
  return copysignf(t, x);
}

// LDS unit index (16B units): [frag][kslice][i15] with XOR swizzle so staging
// writes are 2-way max (free) while read placement stays logically identical.
__device__ __forceinline__ int ldsu(int frag, int kh, int i15) {
  return (frag << 6) | (kh << 4) | (i15 ^ (kh << 2));
}

// ---------------------------------------------------------------------------
// K0: WaT[j][k] = bf16(Wa[k][j])   (1024x1024), LDS-tiled transpose
// ---------------------------------------------------------------------------
__global__ __launch_bounds__(256) void watrans_kernel(
    const float* __restrict__ Wa, ushort* __restrict__ WaT) {
  __shared__ float Ts[64][65];
  const int jb = blockIdx.x & 15, kb = blockIdx.x >> 4;
  const int c = threadIdx.x & 63, r0 = threadIdx.x >> 6;
#pragma unroll
  for (int i = 0; i < 16; ++i) {
    int kl = r0 + 4 * i;
    Ts[c][kl] = Wa[(size_t)(kb * 64 + kl) * UU + jb * 64 + c];
  }
  __syncthreads();
#pragma unroll
  for (int i = 0; i < 16; ++i) {
    int jl = r0 + 4 * i;
    WaT[(size_t)(jb * 64 + jl) * UU + kb * 64 + c] = f2bf(Ts[jl][c]);
  }
}

// ---------------------------------------------------------------------------
// K1: dec[b][j] = h[b] @ Wh_w + Wh_b   (1024 threads, j = tid)
// ---------------------------------------------------------------------------
__global__ __launch_bounds__(1024) void dec_kernel(
    const float* __restrict__ h, const float* __restrict__ Whw,
    const float* __restrict__ Whb, float* __restrict__ dec) {
  int b = blockIdx.x;
  __shared__ float hs[DHH];
  if (threadIdx.x < DHH) hs[threadIdx.x] = h[b * DHH + threadIdx.x];
  __syncthreads();
  int j = threadIdx.x;
  float acc = Whb[j];
#pragma unroll 8
  for (int k = 0; k < DHH; ++k) acc = fmaf(hs[k], Whw[(size_t)k * UU + j], acc);
  dec[b * UU + j] = acc;
}

// ---------------------------------------------------------------------------
// K2: MFMA GEMM (M=65536,N=1024,K=1024) + fused tanh/v epilogue.
// partial[nt][m] = sum_{j in nt-tile} v_j tanh(enc[m][j] + dec[j] + cov[m]*Wc[j])
// 128x128 tile, BK=32, 4 waves 2x2, frags 4x4 of 16x16x32 bf16.
// Grid swizzle: all 8 nt-blocks of one mt share blockIdx%8 -> same XCD L2.
// ---------------------------------------------------------------------------
__global__ __launch_bounds__(256) void e_mfma_kernel(
    const float* __restrict__ a, const ushort* __restrict__ WaT,
    const float* __restrict__ dec, const float* __restrict__ cov,
    const float* __restrict__ Wc, const float* __restrict__ v,
    const int* __restrict__ use_cov_p, float* __restrict__ partial) {
  __shared__ __align__(16) ushort aS[4096];   // 8 KB
  __shared__ __align__(16) ushort bS[4096];   // 8 KB
  __shared__ float dec_s[128], v_s[128], wc_s[128], cov_s[128];
  __shared__ float peL[2][128];

  const int tid = threadIdx.x;
  const int lane = tid & 63;
  const int wid = tid >> 6;
  const int wm = wid >> 1, wn = wid & 1;

  // XCD-locality swizzle (bijective on [0,4096)):
  const int x   = blockIdx.x & 7;
  const int q   = blockIdx.x >> 3;
  const int nt  = q & 7;
  const int mt  = (q >> 3) * 8 + x;

  const int j0 = nt * 128;
  const int row0 = mt * 128;
  const int b = row0 >> 11;
  const int trow0 = row0 & (TXX - 1);

  if (tid < 128) {
    dec_s[tid] = dec[b * UU + j0 + tid];
    v_s[tid] = v[j0 + tid];
    wc_s[tid] = Wc[j0 + tid];
    cov_s[tid] = (*use_cov_p) ? cov[b * TXX + trow0 + tid] : 0.0f;
  }

  f4v zero = {0.f, 0.f, 0.f, 0.f};
  f4v acc[4][4];
#pragma unroll
  for (int mi = 0; mi < 4; ++mi)
#pragma unroll
    for (int ni = 0; ni < 4; ++ni) acc[mi][ni] = zero;

  const float* __restrict__ aRow = a + (size_t)row0 * UU;
  const int arow = tid >> 3;        // 0..31
  const int kq = (tid & 7) * 4;     // 0..28  (4 f32 k-elems)
  const int jrow = tid >> 2;        // 0..63
  const int kc = tid & 3;           // 16B k-chunk within row

  for (int ks = 0; ks < 32; ++ks) {
    const int k0 = ks * 32;
    // --- stage A: 128 rows x 32 k, f32 -> bf16, swizzled store ---
#pragma unroll
    for (int l = 0; l < 4; ++l) {
      const int row = l * 32 + arow;
      float4 va = *(const float4*)(aRow + (size_t)row * UU + k0 + kq);
      ushort4 ub = make_ushort4(f2bf(va.x), f2bf(va.y), f2bf(va.z), f2bf(va.w));
      const int unit = ldsu(row >> 4, kq >> 3, row & 15);
      *(ushort4*)&aS[unit * 8 + (kq & 7)] = ub;
    }
    // --- stage B: 128 j x 32 k bf16; 64B-contiguous global per row ---
#pragma unroll
    for (int l = 0; l < 2; ++l) {
      const int jr = l * 64 + jrow;
      uint4 w = *(const uint4*)(WaT + (size_t)(j0 + jr) * UU + k0 + kc * 8);
      *(uint4*)&bS[ldsu(jr >> 4, kc, jr & 15) * 8] = w;
    }
    __syncthreads();
    s8v af[4], bff[4];
    const int kh = lane >> 4, i15 = lane & 15;
#pragma unroll
    for (int mi = 0; mi < 4; ++mi)
      af[mi] = *(const s8v*)&aS[ldsu((wm << 2) + mi, kh, i15) * 8];
#pragma unroll
    for (int ni = 0; ni < 4; ++ni)
      bff[ni] = *(const s8v*)&bS[ldsu((wn << 2) + ni, kh, i15) * 8];
#pragma unroll
    for (int mi = 0; mi < 4; ++mi)
#pragma unroll
      for (int ni = 0; ni < 4; ++ni)
        acc[mi][ni] = __builtin_amdgcn_mfma_f32_16x16x32_bf16(af[mi], bff[ni], acc[mi][ni], 0, 0, 0);
    __syncthreads();
  }

  // --- epilogue: f = acc + dec[j] + cov[m]*Wc[j]; pe[m] += v[j]*tanh(f) ---
  const int lj = lane & 15, lk = lane >> 4;
  float pe[4][4];
#pragma unroll
  for (int mi = 0; mi < 4; ++mi)
#pragma unroll
    for (int r = 0; r < 4; ++r) pe[mi][r] = 0.f;

#pragma unroll
  for (int mi = 0; mi < 4; ++mi) {
    float cv[4];
#pragma unroll
    for (int r = 0; r < 4; ++r) cv[r] = cov_s[(wm << 6) + (mi << 4) + (lk << 2) + r];
#pragma unroll
    for (int ni = 0; ni < 4; ++ni) {
      const int jl = (wn << 6) + (ni << 4) + lj;
      const float dj = dec_s[jl], wj = wc_s[jl], vj = v_s[jl];
#pragma unroll
      for (int r = 0; r < 4; ++r) {
        float f = acc[mi][ni][r] + dj + cv[r] * wj;
        pe[mi][r] += vj * tanh_fast(f);
      }
    }
  }
#pragma unroll
  for (int mi = 0; mi < 4; ++mi)
#pragma unroll
    for (int r = 0; r < 4; ++r) {
      float s = pe[mi][r];
      s += __shfl_xor(s, 1); s += __shfl_xor(s, 2);
      s += __shfl_xor(s, 4); s += __shfl_xor(s, 8);
      if (lj == 0) peL[wn][(wm << 6) + (mi << 4) + (lk << 2) + r] = s;
    }
  __syncthreads();
  if (tid < 128)
    partial[(size_t)nt * MM + row0 + tid] = peL[0][tid] + peL[1][tid];
}

// ---------------------------------------------------------------------------
// K3: e = sum of 8 partials; masked softmax over TX.
// ---------------------------------------------------------------------------
__global__ __launch_bounds__(256) void softmax_kernel(
    const float* __restrict__ partial, const void* __restrict__ mask,
    const int* __restrict__ use_mask_p, float* __restrict__ alpha) {
  int b = blockIdx.x;
  int tid = threadIdx.x;
  int lane = tid & 63, wv = tid >> 6;
  const unsigned char* m8 = (const unsigned char*)mask;
  const int* m32 = (const int*)mask;
  int um = *use_mask_p;

  __shared__ float es[TXX];
  for (int t = tid; t < TXX; t += 256) {
    float s = 0.f;
#pragma unroll
    for (int nt = 0; nt < 8; ++nt) s += partial[(size_t)nt * MM + b * TXX + t];
    es[t] = s;
  }

  __shared__ int isBoolS;
  if (tid == 0) {
    int anyNZ = 0;
    for (int i = 0; i < 4096; ++i)
      if ((i & 3) && m8[i]) { anyNZ = 1; break; }
    isBoolS = anyNZ;
  }
  __syncthreads();
  const int isBool = isBoolS;

  float m = -1e30f;
  for (int t = tid; t < TXX; t += 256) m = fmaxf(m, es[t]);
#pragma unroll
  for (int o = 32; o > 0; o >>= 1) m = fmaxf(m, __shfl_xor(m, o, 64));
  __shared__ float redm[4];
  if (lane == 0) redm[wv] = m;
  __syncthreads();
  m = fmaxf(fmaxf(redm[0], redm[1]), fmaxf(redm[2], redm[3]));

  float s = 0.f;
  for (int t = tid; t < TXX; t += 256) {
    float w = __expf(es[t] - m);
    if (um) {
      int mv = isBool ? (int)m8[b * TXX + t] : m32[b * TXX + t];
      if (mv == 0) w = 0.f;
    }
    s += w;
  }
#pragma unroll
  for (int o = 32; o > 0; o >>= 1) s += __shfl_xor(s, o, 64);
  __shared__ float reds[4];
  if (lane == 0) reds[wv] = s;
  __syncthreads();
  s = reds[0] + reds[1] + reds[2] + reds[3];
  float inv = 1.0f / s;

  for (int t = tid; t < TXX; t += 256) {
    float w = __expf(es[t] - m);
    if (um) {
      int mv = isBool ? (int)m8[b * TXX + t] : m32[b * TXX + t];
      if (mv == 0) w = 0.f;
    }
    alpha[b * TXX + t] = w * inv;
  }
}

// ---------------------------------------------------------------------------
// K4: cpart[ts][b][d] = sum_{t in ts-chunk} alpha[b,t] * a[b,t,d]
// 512 blocks (32 b x 16 ts), 256 threads x float4 = full 1024-wide row.
// ---------------------------------------------------------------------------
__global__ __launch_bounds__(256) void context_kernel(
    const float* __restrict__ a, const float* __restrict__ alpha,
    float* __restrict__ cpart) {
  const int b = blockIdx.x >> 4;
  const int ts = blockIdx.x & 15;
  const int d4 = threadIdx.x * 4;
  const float* __restrict__ ab  = a + (size_t)(b * TXX + ts * 128) * UU;
  const float* __restrict__ alb = alpha + b * TXX + ts * 128;
  float4 acc = {0.f, 0.f, 0.f, 0.f};
  for (int t = 0; t < 128; t += 4) {
#pragma unroll
    for (int u = 0; u < 4; ++u) {
      float al = alb[t + u];
      float4 va = *(const float4*)(ab + (size_t)(t + u) * UU + d4);
      acc.x = fmaf(al, va.x, acc.x);
      acc.y = fmaf(al, va.y, acc.y);
      acc.z = fmaf(al, va.z, acc.z);
      acc.w = fmaf(al, va.w, acc.w);
    }
  }
  *(float4*)(cpart + (size_t)(ts * BB + b) * UU + d4) = acc;
}

// K5: ctx[b][d] = sum_ts cpart[ts][b][d]
__global__ __launch_bounds__(256) void ctx_reduce_kernel(
    const float* __restrict__ cpart, float* __restrict__ ctx) {
  int i = blockIdx.x * 256 + threadIdx.x;   // over BB*UU
  float s = 0.f;
#pragma unroll
  for (int ts = 0; ts < 16; ++ts) s += cpart[(size_t)ts * BB * UU + i];
  ctx[i] = s;
}

// ---------------------------------------------------------------------------
extern "C" void kernel_launch(void* const* d_in, const int* in_sizes, int n_in,
                              void* d_out, int out_size, void* d_ws, size_t ws_size,
                              hipStream_t stream) {
  const float* a   = (const float*)d_in[0];
  const float* h   = (const float*)d_in[1];
  const float* cov = (const float*)d_in[2];
  const void*  msk = d_in[3];
  const float* Wa  = (const float*)d_in[4];
  const float* Whw = (const float*)d_in[5];
  const float* Whb = (const float*)d_in[6];
  const float* Wc  = (const float*)d_in[7];
  const float* v   = (const float*)d_in[8];
  const int* use_cov  = (const int*)d_in[9];
  const int* use_mask = (const int*)d_in[10];

  float*  dec     = (float*)d_ws;                                  // 128 KB
  ushort* WaT     = (ushort*)((char*)d_ws + 131072);               // 2 MB
  float*  partial = (float*)((char*)d_ws + 131072 + 2097152);      // 2 MB
  float*  cpart   = partial;  // reuse: softmax consumes partial before K4

  float* ctx   = (float*)d_out;
  float* alpha = (float*)d_out + BB * UU;

  watrans_kernel<<<256, 256, 0, stream>>>(Wa, WaT);
  dec_kernel<<<BB, 1024, 0, stream>>>(h, Whw, Whb, dec);
  e_mfma_kernel<<<(MM / 128) * 8, 256, 0, stream>>>(a, WaT, dec, cov, Wc, v, use_cov, partial);
  softmax_kernel<<<BB, 256, 0, stream>>>(partial, msk, use_mask, alpha);
  context_kernel<<<BB * 16, 256, 0, stream>>>(a, alpha, cpart);
  ctx_reduce_kernel<<<BB * UU / 256, 256, 0, stream>>>(cpart, ctx);
}